// Round 13
// baseline (264.680 us; speedup 1.0000x reference)
//
#include <hip/hip_runtime.h>
#include <hip/hip_bf16.h>

#define S 2048
#define H 1024
#define NH 16
#define DH 64
#define RV 32
#define BK 32
#define NSPLIT 2
#define SKEYS (S / NSPLIT)

typedef __hip_bfloat16 bf16;
typedef short bf16x8 __attribute__((ext_vector_type(8)));
typedef float f32x4 __attribute__((ext_vector_type(4)));
typedef float f32x16 __attribute__((ext_vector_type(16)));

__device__ __forceinline__ float b2f(bf16 v) { return __bfloat162float(v); }
__device__ __forceinline__ unsigned short f2bbits(float x) {
    __hip_bfloat16 b = __float2bfloat16(x);
    return *reinterpret_cast<unsigned short*>(&b);
}
__device__ __forceinline__ float ldf(const void* p, int i, int f) {
    return f ? ((const float*)p)[i] : b2f(((const bf16*)p)[i]);
}
__device__ __forceinline__ void gl_lds16(const bf16* g, bf16* l) {
    __builtin_amdgcn_global_load_lds(
        (const __attribute__((address_space(1))) void*)g,
        (__attribute__((address_space(3))) void*)l,
        16, 0, 0);
}

// ---------------- pack rel_ids + att_mask into one byte; block 0 sniffs dtype
__global__ __launch_bounds__(256) void pack_rm(
    const int* __restrict__ rel_ids, const int* __restrict__ att_mask,
    unsigned char* __restrict__ PBg,
    const unsigned int* __restrict__ xw, int* __restrict__ flag)
{
    if (blockIdx.x == 0) {
        __shared__ int cnt;
        if (threadIdx.x == 0) cnt = 0;
        __syncthreads();
        unsigned int w = xw[threadIdx.x];
        unsigned int ex = ((w & 0xffffu) >> 7) & 0xffu;
        int big = (ex > 134u) ? 1 : 0;
        #pragma unroll
        for (int off = 32; off > 0; off >>= 1) big += __shfl_xor(big, off, 64);
        if ((threadIdx.x & 63) == 0) atomicAdd(&cnt, big);
        __syncthreads();
        if (threadIdx.x == 0) *flag = (cnt > 60) ? 1 : 0;
    }
    int i = blockIdx.x * 256 + threadIdx.x;
    int4 rid = ((const int4*)rel_ids)[i];
    int4 msk = ((const int4*)att_mask)[i];
    uchar4 o;
    o.x = (unsigned char)(rid.x | ((msk.x == 0) << 7));
    o.y = (unsigned char)(rid.y | ((msk.y == 0) << 7));
    o.z = (unsigned char)(rid.z | ((msk.z == 0) << 7));
    o.w = (unsigned char)(rid.w | ((msk.w == 0) << 7));
    ((uchar4*)PBg)[i] = o;
}

// ---------------- weight transpose (z<4) + x conversion (z==4) -------------
__global__ __launch_bounds__(256) void prep_inputs(
    const void* __restrict__ W0, const void* __restrict__ W1,
    const void* __restrict__ W2, const void* __restrict__ W3,
    bf16* __restrict__ T0, bf16* __restrict__ T1,
    bf16* __restrict__ T2, bf16* __restrict__ T3,
    const void* __restrict__ x, bf16* __restrict__ xb,
    const int* __restrict__ flag)
{
    const int f = *flag;
    if (blockIdx.z == 4) {
        const int c = blockIdx.y * 16 + blockIdx.x;
        #pragma unroll
        for (int it = 0; it < 8; ++it) {
            int i = c * 8192 + it * 1024 + threadIdx.x * 4;
            if (f) {
                float4 v = *(const float4*)((const float*)x + i);
                ushort4 o;
                o.x = f2bbits(v.x); o.y = f2bbits(v.y);
                o.z = f2bbits(v.z); o.w = f2bbits(v.w);
                *(ushort4*)&xb[i] = o;
            } else {
                *(ushort4*)&xb[i] = *(const ushort4*)((const bf16*)x + i);
            }
        }
        return;
    }
    const void* W; bf16* T;
    switch (blockIdx.z) {
        case 0:  W = W0; T = T0; break;
        case 1:  W = W1; T = T1; break;
        case 2:  W = W2; T = T2; break;
        default: W = W3; T = T3; break;
    }
    __shared__ unsigned short Ts[64][68];
    const int t = threadIdx.x;
    const int tx = t & 15, ty = t >> 4;
    const int n0 = blockIdx.x * 64;
    const int k0 = blockIdx.y * 64;
    #pragma unroll
    for (int it = 0; it < 4; ++it) {
        int k = ty + it * 16;
        int base = (k0 + k) * H + n0 + tx * 4;
        #pragma unroll
        for (int e = 0; e < 4; ++e)
            Ts[k][tx * 4 + e] = f2bbits(ldf(W, base + e, f));
    }
    __syncthreads();
    #pragma unroll
    for (int it = 0; it < 4; ++it) {
        int n = ty + it * 16;
        ushort4 o;
        o.x = Ts[tx * 4 + 0][n];
        o.y = Ts[tx * 4 + 1][n];
        o.z = Ts[tx * 4 + 2][n];
        o.w = Ts[tx * 4 + 3][n];
        *(ushort4*)&T[(size_t)(n0 + n) * H + k0 + tx * 4] = o;
    }
}

// ---------------- templated BMxBN MFMA GEMM core (m97 style) ---------------
template<int BM, int BN>
__device__ __forceinline__ void gemm_bt_core(
    const bf16* __restrict__ A, const bf16* __restrict__ BT,
    f32x4 (&acc)[BM / 32][BN / 32])
{
    constexpr int MT = BM / 32, NT = BN / 32;
    const int tid = threadIdx.x;
    const int w = tid >> 6, lane = tid & 63;
    const int l15 = lane & 15, quad = lane >> 4;
    const int wm = (w & 1) * (BM / 2), wn = (w >> 1) * (BN / 2);
    const int rowb = blockIdx.y * BM;
    const int colb = blockIdx.x * BN;

    __shared__ bf16 As[BM * BK];
    __shared__ bf16 Bs[BN * BK];

    for (int kb = 0; kb < H; kb += BK) {
        #pragma unroll
        for (int j = 0; j < BM / 64; ++j) {
            int i = j * 256 + w * 64 + lane;
            gl_lds16(&A[(size_t)(rowb + (i >> 2)) * H + kb + (i & 3) * 8],
                     &As[(size_t)(j * 256 + w * 64) * 8]);
        }
        #pragma unroll
        for (int j = 0; j < BN / 64; ++j) {
            int i = j * 256 + w * 64 + lane;
            gl_lds16(&BT[(size_t)(colb + (i >> 2)) * H + kb + (i & 3) * 8],
                     &Bs[(size_t)(j * 256 + w * 64) * 8]);
        }
        __syncthreads();

        bf16x8 af[MT], bfr[NT];
        #pragma unroll
        for (int mt = 0; mt < MT; ++mt)
            af[mt] = *(const bf16x8*)&As[(wm + mt * 16 + l15) * BK + quad * 8];
        #pragma unroll
        for (int nt = 0; nt < NT; ++nt)
            bfr[nt] = *(const bf16x8*)&Bs[(wn + nt * 16 + l15) * BK + quad * 8];
        #pragma unroll
        for (int mt = 0; mt < MT; ++mt)
            #pragma unroll
            for (int nt = 0; nt < NT; ++nt)
                acc[mt][nt] = __builtin_amdgcn_mfma_f32_16x16x32_bf16(
                    af[mt], bfr[nt], acc[mt][nt], 0, 0, 0);
        __syncthreads();
    }
}

// ---------------- QKV MFMA GEMM (128x64 tiles, 768 blocks = 3/CU) ----------
__global__ __launch_bounds__(256) void qkv_mfma(
    const bf16* __restrict__ xb,
    const bf16* __restrict__ WTq, const bf16* __restrict__ WTk,
    const bf16* __restrict__ WTv,
    const void* __restrict__ bq, const void* __restrict__ bk,
    const void* __restrict__ bv,
    bf16* __restrict__ Qb, bf16* __restrict__ Kb, bf16* __restrict__ VT,
    const int* __restrict__ flag)
{
    const bf16* BT; const void* bias;
    if (blockIdx.z == 0)      { BT = WTq; bias = bq; }
    else if (blockIdx.z == 1) { BT = WTk; bias = bk; }
    else                      { BT = WTv; bias = bv; }
    const int f = *flag;

    f32x4 acc[4][2];
    #pragma unroll
    for (int a = 0; a < 4; ++a)
        #pragma unroll
        for (int b = 0; b < 2; ++b) acc[a][b] = (f32x4)0.f;

    gemm_bt_core<128, 64>(xb, BT, acc);

    const int tid = threadIdx.x;
    const int w = tid >> 6, lane = tid & 63;
    const int l15 = lane & 15, quad = lane >> 4;
    const int wm = (w & 1) * 64, wn = (w >> 1) * 32;
    const int rowb = blockIdx.y * 128;
    const int colb = blockIdx.x * 64;

    float bvv[2];
    #pragma unroll
    for (int nt = 0; nt < 2; ++nt)
        bvv[nt] = ldf(bias, colb + wn + nt * 16 + l15, f);

    if (blockIdx.z == 2) {
        #pragma unroll
        for (int mt = 0; mt < 4; ++mt)
            #pragma unroll
            for (int nt = 0; nt < 2; ++nt) {
                int m0 = rowb + wm + mt * 16 + quad * 4;
                int n = colb + wn + nt * 16 + l15;
                ushort4 o;
                o.x = f2bbits(acc[mt][nt][0] + bvv[nt]);
                o.y = f2bbits(acc[mt][nt][1] + bvv[nt]);
                o.z = f2bbits(acc[mt][nt][2] + bvv[nt]);
                o.w = f2bbits(acc[mt][nt][3] + bvv[nt]);
                *(ushort4*)&VT[(size_t)n * S + m0] = o;
            }
    } else {
        bf16* out = (blockIdx.z == 0) ? Qb : Kb;
        const float scale = (blockIdx.z == 1) ? 0.125f : 1.0f;
        #pragma unroll
        for (int mt = 0; mt < 4; ++mt)
            #pragma unroll
            for (int nt = 0; nt < 2; ++nt)
                #pragma unroll
                for (int r = 0; r < 4; ++r) {
                    int m = rowb + wm + mt * 16 + quad * 4 + r;
                    int n = colb + wn + nt * 16 + l15;
                    out[(size_t)m * H + n] =
                        __float2bfloat16((acc[mt][nt][r] + bvv[nt]) * scale);
                }
    }
}

// ---------------- output MFMA GEMM (64x64 tiles, 512 blocks = 2/CU) --------
__global__ __launch_bounds__(256) void out_mfma(
    const bf16* __restrict__ Cb, const bf16* __restrict__ WoT,
    const void* __restrict__ bias, void* __restrict__ out,
    const int* __restrict__ flag)
{
    const int f = *flag;
    f32x4 acc[2][2];
    #pragma unroll
    for (int a = 0; a < 2; ++a)
        #pragma unroll
        for (int b = 0; b < 2; ++b) acc[a][b] = (f32x4)0.f;

    gemm_bt_core<64, 64>(Cb, WoT, acc);

    const int tid = threadIdx.x;
    const int w = tid >> 6, lane = tid & 63;
    const int l15 = lane & 15, quad = lane >> 4;
    const int wm = (w & 1) * 32, wn = (w >> 1) * 32;
    const int rowb = blockIdx.y * 64;
    const int colb = blockIdx.x * 64;

    float bvv[2];
    #pragma unroll
    for (int nt = 0; nt < 2; ++nt)
        bvv[nt] = ldf(bias, colb + wn + nt * 16 + l15, f);

    #pragma unroll
    for (int mt = 0; mt < 2; ++mt)
        #pragma unroll
        for (int nt = 0; nt < 2; ++nt)
            #pragma unroll
            for (int r = 0; r < 4; ++r) {
                int m = rowb + wm + mt * 16 + quad * 4 + r;
                int n = colb + wn + nt * 16 + l15;
                float v = acc[mt][nt][r] + bvv[nt];
                if (f) ((float*)out)[(size_t)m * H + n] = v;
                else   ((bf16*)out)[(size_t)m * H + n] = __float2bfloat16(v);
            }
}

// ---------------- MFMA flash attention, 32x32x16 core -----------------------
// block = 64 q x 1 head x 1 split; 4 waves = (wq x wk); wave computes
// S^T[32k][32q] = K.Q^T (Q from global regs), P kept IN REGISTERS and fed to
// O^T += V^T.P as B-operand via one shfl_xor(32) exchange. DS ops/lane/tile
// 26 -> 12, mfma issues 16 -> 8 vs the 16x16 version.
__global__ __launch_bounds__(256, 4) void attn_mfma(
    const bf16* __restrict__ Qb, const bf16* __restrict__ Kb,
    const bf16* __restrict__ VT,
    const void* __restrict__ rel_emb, const void* __restrict__ rel_bias,
    const unsigned char* __restrict__ PBg,
    float* __restrict__ Op, float* __restrict__ Lp,
    const int* __restrict__ flag)
{
    const int head = blockIdx.x;
    const int qb = blockIdx.y;
    const int split = blockIdx.z;
    const int q0 = qb * 64;
    const int kt0 = split * SKEYS;
    const int tid = threadIdx.x;
    const int lane = tid & 63;
    const int l15 = lane & 15;
    const int quad = lane >> 4;
    const int l31 = lane & 31;
    const int hf = lane >> 5;           // row-half within 32x32 fragments
    const int wq = (tid >> 6) & 1;      // q-group (32 rows)
    const int wk = tid >> 7;            // key-half of each 64-key tile
    const int f = *flag;

    union SharedU {
        struct { short Ks[64][72]; short Vs[64][72]; } ld;  // in-loop tiles
        short Es[32][64];                                   // init only
        float Ob[2][64][33];                                // epilogue merge
    };
    __shared__ SharedU U;
    __shared__ float Rl[64][33];
    __shared__ float Rbias[32];
    __shared__ float Ll[2][32];

    // ---- prefetch tile 0 (K/V into regs for LDS staging; PB per-lane) ----
    uint4 kp[2], vp[2];
    unsigned int pb[4];
    {
        #pragma unroll
        for (int j = 0; j < 2; ++j) {
            int slot = j * 256 + tid;
            int r = slot >> 3, c = slot & 7;
            kp[j] = *(const uint4*)&Kb[(size_t)(kt0 + r) * H + head * DH + c * 8];
            vp[j] = *(const uint4*)&VT[(size_t)(head * DH + r) * S + kt0 + c * 8];
        }
    }
    const int qcol = q0 + wq * 32 + l31;
    const unsigned char* pbrow = PBg + (size_t)qcol * S;
    #pragma unroll
    for (int g = 0; g < 4; ++g)
        pb[g] = *(const unsigned int*)&pbrow[kt0 + wk * 32 + g * 8 + hf * 4];

    // ---- Q fragments: 16x16 A-layout for Rl init, 32x32 B-layout for loop --
    bf16x8 iq0, iq1;
    {
        const bf16* qrow = Qb + (size_t)(q0 + (tid >> 6) * 16 + l15) * H + head * DH;
        iq0 = *(const bf16x8*)&qrow[quad * 8];
        iq1 = *(const bf16x8*)&qrow[32 + quad * 8];
    }
    bf16x8 bq[4];
    #pragma unroll
    for (int s = 0; s < 4; ++s)
        bq[s] = *(const bf16x8*)&Qb[(size_t)qcol * H + head * DH + s * 16 + hf * 8];

    // ---- stage rel_emb/8 + rel_bias/8; Rl via 16x16 MFMA ----
    {
        int r = tid >> 3, c8 = (tid & 7) * 8;
        unsigned short os[8];
        if (f) {
            const float* src = (const float*)rel_emb + (r * NH + head) * DH + c8;
            #pragma unroll
            for (int e = 0; e < 8; ++e) os[e] = f2bbits(src[e] * 0.125f);
        } else {
            const bf16* src = (const bf16*)rel_emb + (r * NH + head) * DH + c8;
            #pragma unroll
            for (int e = 0; e < 8; ++e) os[e] = f2bbits(b2f(src[e]) * 0.125f);
        }
        *(ushort4*)&U.Es[r][c8]     = *(ushort4*)&os[0];
        *(ushort4*)&U.Es[r][c8 + 4] = *(ushort4*)&os[4];
        if (tid < RV) Rbias[tid] = ldf(rel_bias, tid * NH + head, f) * 0.125f;
    }
    __syncthreads();

    {
        const int w16 = tid >> 6;
        #pragma unroll
        for (int nt = 0; nt < 2; ++nt) {
            bf16x8 be0 = *(const bf16x8*)&U.Es[nt * 16 + l15][quad * 8];
            bf16x8 be1 = *(const bf16x8*)&U.Es[nt * 16 + l15][32 + quad * 8];
            f32x4 c = (f32x4)0.f;
            c = __builtin_amdgcn_mfma_f32_16x16x32_bf16(iq0, be0, c, 0, 0, 0);
            c = __builtin_amdgcn_mfma_f32_16x16x32_bf16(iq1, be1, c, 0, 0, 0);
            float rb = Rbias[nt * 16 + l15];
            #pragma unroll
            for (int r = 0; r < 4; ++r)
                Rl[w16 * 16 + quad * 4 + r][nt * 16 + l15] = c[r] + rb;
        }
    }
    __syncthreads();   // Rl done; Es dead before Ks/Vs overwrite

    f32x16 Ov[2];
    Ov[0] = (f32x16)0.f; Ov[1] = (f32x16)0.f;
    float llocal = 0.f;
    const float* rlrow = &Rl[wq * 32 + l31][0];

    for (int kt = kt0; kt < kt0 + SKEYS; kt += 64) {
        // ---- store prefetched K/V tiles to LDS ----
        #pragma unroll
        for (int j = 0; j < 2; ++j) {
            int slot = j * 256 + tid;
            int r = slot >> 3, c = slot & 7;
            *(uint4*)&U.ld.Ks[r][c * 8] = kp[j];
            *(uint4*)&U.ld.Vs[r][c * 8] = vp[j];
        }
        unsigned int pbc[4];
        #pragma unroll
        for (int g = 0; g < 4; ++g) pbc[g] = pb[g];
        __syncthreads();

        // ---- prefetch next tile ----
        if (kt + 64 < kt0 + SKEYS) {
            #pragma unroll
            for (int j = 0; j < 2; ++j) {
                int slot = j * 256 + tid;
                int r = slot >> 3, c = slot & 7;
                kp[j] = *(const uint4*)&Kb[(size_t)(kt + 64 + r) * H + head * DH + c * 8];
                vp[j] = *(const uint4*)&VT[(size_t)(head * DH + r) * S + kt + 64 + c * 8];
            }
            #pragma unroll
            for (int g = 0; g < 4; ++g)
                pb[g] = *(const unsigned int*)&pbrow[kt + 64 + wk * 32 + g * 8 + hf * 4];
        }

        // ---- S^T[32k][32q] = (K/8).Q^T : 4 chained 32x32x16 over d ----
        f32x16 st = (f32x16)0.f;
        #pragma unroll
        for (int s = 0; s < 4; ++s) {
            bf16x8 ak = *(const bf16x8*)&U.ld.Ks[wk * 32 + l31][s * 16 + hf * 8];
            st = __builtin_amdgcn_mfma_f32_32x32x16_bf16(ak, bq[s], st, 0, 0, 0);
        }

        // ---- p = exp(s + rl), masked -> 0; per-lane l ----
        // C layout: reg r=g*4+c -> local key k = 8g + 4hf + c, col q = l31.
        float pv[16];
        #pragma unroll
        for (int g = 0; g < 4; ++g) {
            unsigned int pw = pbc[g];
            #pragma unroll
            for (int c = 0; c < 4; ++c) {
                unsigned int b = pw >> (8 * c);
                float rl = rlrow[b & 63u];
                float pe = __expf(st[g * 4 + c] + rl);
                pv[g * 4 + c] = (b & 0x80u) ? 0.f : pe;
            }
            llocal += (pv[g * 4] + pv[g * 4 + 1]) + (pv[g * 4 + 2] + pv[g * 4 + 3]);
        }

        // ---- build PV B-frags in registers via half-row exchange ----
        float sendv[8], recv[8];
        #pragma unroll
        for (int c = 0; c < 4; ++c) {
            sendv[c]     = hf ? pv[c]      : pv[4 + c];
            sendv[4 + c] = hf ? pv[8 + c]  : pv[12 + c];
        }
        #pragma unroll
        for (int i = 0; i < 8; ++i) recv[i] = __shfl_xor(sendv[i], 32, 64);
        unsigned short b0[8], b1[8];
        #pragma unroll
        for (int c = 0; c < 4; ++c) {
            b0[c]     = f2bbits(hf ? recv[c]     : pv[c]);
            b0[4 + c] = f2bbits(hf ? pv[4 + c]   : recv[c]);
            b1[c]     = f2bbits(hf ? recv[4 + c] : pv[8 + c]);
            b1[4 + c] = f2bbits(hf ? pv[12 + c]  : recv[4 + c]);
        }
        bf16x8 bp0 = *(bf16x8*)b0, bp1 = *(bf16x8*)b1;

        // ---- O^T[64d][32q] += V^T[64d][32k].P[32k][32q] ----
        #pragma unroll
        for (int mt = 0; mt < 2; ++mt) {
            bf16x8 av0 = *(const bf16x8*)&U.ld.Vs[mt * 32 + l31][wk * 32 + hf * 8];
            bf16x8 av1 = *(const bf16x8*)&U.ld.Vs[mt * 32 + l31][wk * 32 + 16 + hf * 8];
            Ov[mt] = __builtin_amdgcn_mfma_f32_32x32x16_bf16(av0, bp0, Ov[mt], 0, 0, 0);
            Ov[mt] = __builtin_amdgcn_mfma_f32_32x32x16_bf16(av1, bp1, Ov[mt], 0, 0, 0);
        }
        __syncthreads();
    }

    // ---- epilogue: merge wk halves in LDS, coalesced partial write ----
    float lsum = llocal + __shfl_xor(llocal, 32, 64);
    if (wk == 0) {
        #pragma unroll
        for (int mt = 0; mt < 2; ++mt)
            #pragma unroll
            for (int r = 0; r < 16; ++r)
                U.Ob[wq][mt * 32 + (r & 3) + 8 * (r >> 2) + 4 * hf][l31] = Ov[mt][r];
        if (hf == 0) Ll[wq][l31] = lsum;
    }
    __syncthreads();
    if (wk == 1) {
        #pragma unroll
        for (int mt = 0; mt < 2; ++mt)
            #pragma unroll
            for (int r = 0; r < 16; ++r)
                U.Ob[wq][mt * 32 + (r & 3) + 8 * (r >> 2) + 4 * hf][l31] += Ov[mt][r];
        if (hf == 0) Ll[wq][l31] += lsum;
    }
    __syncthreads();

    const size_t base = ((size_t)split * NH + head) * 32 + qb;
    float* Ob = Op + base * 4096;
    {
        int q = tid >> 2, d0 = (tid & 3) * 16;
        #pragma unroll
        for (int j = 0; j < 4; ++j) {
            float4 v;
            v.x = U.Ob[q >> 5][d0 + j * 4 + 0][q & 31];
            v.y = U.Ob[q >> 5][d0 + j * 4 + 1][q & 31];
            v.z = U.Ob[q >> 5][d0 + j * 4 + 2][q & 31];
            v.w = U.Ob[q >> 5][d0 + j * 4 + 3][q & 31];
            *(float4*)&Ob[q * 64 + d0 + j * 4] = v;
        }
        if ((tid & 3) == 0) Lp[base * 64 + q] = Ll[q >> 5][q & 31];
    }
}

// ---------------- merge split partials -> Cb bf16 --------------------------
__global__ __launch_bounds__(256) void reduce_splits(
    const float* __restrict__ Op, const float* __restrict__ Lp,
    bf16* __restrict__ Cb)
{
    const int h = blockIdx.x;
    const int qb = blockIdx.y;
    const int q0 = qb * 64;
    const int tid = threadIdx.x;
    const int q = tid >> 2;
    const int d0 = (tid & 3) * 16;

    const size_t b0 = ((size_t)0 * NH + h) * 32 + qb;
    const size_t b1 = ((size_t)1 * NH + h) * 32 + qb;

    float l = Lp[b0 * 64 + q] + Lp[b1 * 64 + q];
    float inv = 1.0f / l;

    const float4* O0 = (const float4*)(Op + b0 * 4096 + q * 64 + d0);
    const float4* O1 = (const float4*)(Op + b1 * 4096 + q * 64 + d0);
    bf16* outp = Cb + (size_t)(q0 + q) * H + h * DH + d0;
    #pragma unroll
    for (int j = 0; j < 4; ++j) {
        float4 v0 = O0[j], v1 = O1[j];
        ushort4 o;
        o.x = f2bbits((v0.x + v1.x) * inv);
        o.y = f2bbits((v0.y + v1.y) * inv);
        o.z = f2bbits((v0.z + v1.z) * inv);
        o.w = f2bbits((v0.w + v1.w) * inv);
        *(ushort4*)&outp[j * 4] = o;
    }
}

extern "C" void kernel_launch(void* const* d_in, const int* in_sizes, int n_in,
                              void* d_out, int out_size, void* d_ws, size_t ws_size,
                              hipStream_t stream)
{
    const void* x        = d_in[0];
    const int*  att_mask = (const int*)d_in[1];
    const int*  rel_ids  = (const int*)d_in[2];
    const void* Wq = d_in[3];
    const void* bq = d_in[4];
    const void* Wk = d_in[5];
    const void* bk = d_in[6];
    const void* Wv = d_in[7];
    const void* bv = d_in[8];
    const void* rel_emb  = d_in[9];
    const void* rel_bias = d_in[10];
    const void* Wo = d_in[11];
    const void* bo = d_in[12];

    char* p = (char*)d_ws;
    bf16* xb  = (bf16*)p; p += (size_t)S * H * 2;
    bf16* WTq = (bf16*)p; p += (size_t)H * H * 2;
    bf16* WTk = (bf16*)p; p += (size_t)H * H * 2;
    bf16* WTv = (bf16*)p; p += (size_t)H * H * 2;
    bf16* WoT = (bf16*)p; p += (size_t)H * H * 2;
    bf16* Qb  = (bf16*)p; p += (size_t)S * H * 2;
    bf16* Kb  = (bf16*)p; p += (size_t)S * H * 2;
    bf16* VT  = (bf16*)p; p += (size_t)S * H * 2;
    bf16* Cb  = (bf16*)p; p += (size_t)S * H * 2;
    unsigned char* PBg = (unsigned char*)p; p += (size_t)S * S;
    float* Op = (float*)p; p += (size_t)NSPLIT * NH * 32 * 64 * 64 * 4;
    float* Lp = (float*)p; p += (size_t)NSPLIT * NH * 32 * 64 * 4;
    int* flag = (int*)p;

    pack_rm<<<(S * S) / 1024, 256, 0, stream>>>(
        rel_ids, att_mask, PBg, (const unsigned int*)x, flag);

    prep_inputs<<<dim3(H / 64, H / 64, 5), 256, 0, stream>>>(
        Wq, Wk, Wv, Wo, WTq, WTk, WTv, WoT, x, xb, flag);

    qkv_mfma<<<dim3(H / 64, S / 128, 3), 256, 0, stream>>>(
        xb, WTq, WTk, WTv, bq, bk, bv, Qb, Kb, VT, flag);

    attn_mfma<<<dim3(NH, S / 64, NSPLIT), 256, 0, stream>>>(
        Qb, Kb, VT, rel_emb, rel_bias, PBg, Op, Lp, flag);

    reduce_splits<<<dim3(NH, S / 64), 256, 0, stream>>>(Op, Lp, Cb);

    out_mfma<<<dim3(H / 64, S / 64), 256, 0, stream>>>(Cb, WoT, bo, d_out, flag);
}

// Round 14
// 250.506 us; speedup vs baseline: 1.0566x; 1.0566x over previous
//
#include <hip/hip_runtime.h>
#include <hip/hip_bf16.h>

#define S 2048
#define H 1024
#define NH 16
#define DH 64
#define RV 32
#define BK 32
#define NSPLIT 2
#define SKEYS (S / NSPLIT)

typedef __hip_bfloat16 bf16;
typedef short bf16x8 __attribute__((ext_vector_type(8)));
typedef float f32x4 __attribute__((ext_vector_type(4)));

__device__ __forceinline__ float b2f(bf16 v) { return __bfloat162float(v); }
__device__ __forceinline__ unsigned short f2bbits(float x) {
    __hip_bfloat16 b = __float2bfloat16(x);
    return *reinterpret_cast<unsigned short*>(&b);
}
__device__ __forceinline__ float ldf(const void* p, int i, int f) {
    return f ? ((const float*)p)[i] : b2f(((const bf16*)p)[i]);
}
__device__ __forceinline__ void gl_lds16(const bf16* g, bf16* l) {
    __builtin_amdgcn_global_load_lds(
        (const __attribute__((address_space(1))) void*)g,
        (__attribute__((address_space(3))) void*)l,
        16, 0, 0);
}

// ---- combined prep: weight transpose (z<4), x convert (z==4), pack (z>=5) --
// Every block self-computes the dtype flag from x's first 256 words (no
// cross-block ordering dependency); block (0,0,0) publishes it for later
// launches.
__global__ __launch_bounds__(256) void prep_inputs(
    const void* __restrict__ W0, const void* __restrict__ W1,
    const void* __restrict__ W2, const void* __restrict__ W3,
    bf16* __restrict__ T0, bf16* __restrict__ T1,
    bf16* __restrict__ T2, bf16* __restrict__ T3,
    const void* __restrict__ x, bf16* __restrict__ xb,
    const int* __restrict__ rel_ids, const int* __restrict__ att_mask,
    unsigned char* __restrict__ PBg, int* __restrict__ flag)
{
    __shared__ int cnt;
    if (threadIdx.x == 0) cnt = 0;
    __syncthreads();
    {
        unsigned int wrd = ((const unsigned int*)x)[threadIdx.x];
        unsigned int ex = ((wrd & 0xffffu) >> 7) & 0xffu;
        int big = (ex > 134u) ? 1 : 0;
        #pragma unroll
        for (int off = 32; off > 0; off >>= 1) big += __shfl_xor(big, off, 64);
        if ((threadIdx.x & 63) == 0) atomicAdd(&cnt, big);
    }
    __syncthreads();
    const int f = (cnt > 60) ? 1 : 0;
    if (blockIdx.z == 0 && blockIdx.x == 0 && blockIdx.y == 0 && threadIdx.x == 0)
        *flag = f;

    if (blockIdx.z >= 5) {
        // pack rel_ids + att_mask -> 1 byte: rid | (mask==0)<<7
        int base = ((blockIdx.z - 5) * 256 + blockIdx.y * 16 + blockIdx.x) * 1024
                   + threadIdx.x;
        #pragma unroll
        for (int it = 0; it < 4; ++it) {
            int i = base + it * 256;
            int4 rid = ((const int4*)rel_ids)[i];
            int4 msk = ((const int4*)att_mask)[i];
            uchar4 o;
            o.x = (unsigned char)(rid.x | ((msk.x == 0) << 7));
            o.y = (unsigned char)(rid.y | ((msk.y == 0) << 7));
            o.z = (unsigned char)(rid.z | ((msk.z == 0) << 7));
            o.w = (unsigned char)(rid.w | ((msk.w == 0) << 7));
            ((uchar4*)PBg)[i] = o;
        }
        return;
    }
    if (blockIdx.z == 4) {
        const int c = blockIdx.y * 16 + blockIdx.x;
        #pragma unroll
        for (int it = 0; it < 8; ++it) {
            int i = c * 8192 + it * 1024 + threadIdx.x * 4;
            if (f) {
                float4 v = *(const float4*)((const float*)x + i);
                ushort4 o;
                o.x = f2bbits(v.x); o.y = f2bbits(v.y);
                o.z = f2bbits(v.z); o.w = f2bbits(v.w);
                *(ushort4*)&xb[i] = o;
            } else {
                *(ushort4*)&xb[i] = *(const ushort4*)((const bf16*)x + i);
            }
        }
        return;
    }
    const void* W; bf16* T;
    switch (blockIdx.z) {
        case 0:  W = W0; T = T0; break;
        case 1:  W = W1; T = T1; break;
        case 2:  W = W2; T = T2; break;
        default: W = W3; T = T3; break;
    }
    __shared__ unsigned short Ts[64][68];
    const int t = threadIdx.x;
    const int tx = t & 15, ty = t >> 4;
    const int n0 = blockIdx.x * 64;
    const int k0 = blockIdx.y * 64;
    #pragma unroll
    for (int it = 0; it < 4; ++it) {
        int k = ty + it * 16;
        int base = (k0 + k) * H + n0 + tx * 4;
        #pragma unroll
        for (int e = 0; e < 4; ++e)
            Ts[k][tx * 4 + e] = f2bbits(ldf(W, base + e, f));
    }
    __syncthreads();
    #pragma unroll
    for (int it = 0; it < 4; ++it) {
        int n = ty + it * 16;
        ushort4 o;
        o.x = Ts[tx * 4 + 0][n];
        o.y = Ts[tx * 4 + 1][n];
        o.z = Ts[tx * 4 + 2][n];
        o.w = Ts[tx * 4 + 3][n];
        *(ushort4*)&T[(size_t)(n0 + n) * H + k0 + tx * 4] = o;
    }
}

// ---------------- templated BMxBN MFMA GEMM core (m97 style) ---------------
template<int BM, int BN>
__device__ __forceinline__ void gemm_bt_core(
    const bf16* __restrict__ A, const bf16* __restrict__ BT,
    f32x4 (&acc)[BM / 32][BN / 32])
{
    constexpr int MT = BM / 32, NT = BN / 32;
    const int tid = threadIdx.x;
    const int w = tid >> 6, lane = tid & 63;
    const int l15 = lane & 15, quad = lane >> 4;
    const int wm = (w & 1) * (BM / 2), wn = (w >> 1) * (BN / 2);
    const int rowb = blockIdx.y * BM;
    const int colb = blockIdx.x * BN;

    __shared__ bf16 As[BM * BK];
    __shared__ bf16 Bs[BN * BK];

    for (int kb = 0; kb < H; kb += BK) {
        #pragma unroll
        for (int j = 0; j < BM / 64; ++j) {
            int i = j * 256 + w * 64 + lane;
            gl_lds16(&A[(size_t)(rowb + (i >> 2)) * H + kb + (i & 3) * 8],
                     &As[(size_t)(j * 256 + w * 64) * 8]);
        }
        #pragma unroll
        for (int j = 0; j < BN / 64; ++j) {
            int i = j * 256 + w * 64 + lane;
            gl_lds16(&BT[(size_t)(colb + (i >> 2)) * H + kb + (i & 3) * 8],
                     &Bs[(size_t)(j * 256 + w * 64) * 8]);
        }
        __syncthreads();

        bf16x8 af[MT], bfr[NT];
        #pragma unroll
        for (int mt = 0; mt < MT; ++mt)
            af[mt] = *(const bf16x8*)&As[(wm + mt * 16 + l15) * BK + quad * 8];
        #pragma unroll
        for (int nt = 0; nt < NT; ++nt)
            bfr[nt] = *(const bf16x8*)&Bs[(wn + nt * 16 + l15) * BK + quad * 8];
        #pragma unroll
        for (int mt = 0; mt < MT; ++mt)
            #pragma unroll
            for (int nt = 0; nt < NT; ++nt)
                acc[mt][nt] = __builtin_amdgcn_mfma_f32_16x16x32_bf16(
                    af[mt], bfr[nt], acc[mt][nt], 0, 0, 0);
        __syncthreads();
    }
}

// ---------------- QKV MFMA GEMM (128x64 tiles, 768 blocks = 3/CU) ----------
__global__ __launch_bounds__(256) void qkv_mfma(
    const bf16* __restrict__ xb,
    const bf16* __restrict__ WTq, const bf16* __restrict__ WTk,
    const bf16* __restrict__ WTv,
    const void* __restrict__ bq, const void* __restrict__ bk,
    const void* __restrict__ bv,
    bf16* __restrict__ Qb, bf16* __restrict__ Kb, bf16* __restrict__ VT,
    const int* __restrict__ flag)
{
    const bf16* BT; const void* bias;
    if (blockIdx.z == 0)      { BT = WTq; bias = bq; }
    else if (blockIdx.z == 1) { BT = WTk; bias = bk; }
    else                      { BT = WTv; bias = bv; }
    const int f = *flag;

    f32x4 acc[4][2];
    #pragma unroll
    for (int a = 0; a < 4; ++a)
        #pragma unroll
        for (int b = 0; b < 2; ++b) acc[a][b] = (f32x4)0.f;

    gemm_bt_core<128, 64>(xb, BT, acc);

    const int tid = threadIdx.x;
    const int w = tid >> 6, lane = tid & 63;
    const int l15 = lane & 15, quad = lane >> 4;
    const int wm = (w & 1) * 64, wn = (w >> 1) * 32;
    const int rowb = blockIdx.y * 128;
    const int colb = blockIdx.x * 64;

    float bvv[2];
    #pragma unroll
    for (int nt = 0; nt < 2; ++nt)
        bvv[nt] = ldf(bias, colb + wn + nt * 16 + l15, f);

    if (blockIdx.z == 2) {
        #pragma unroll
        for (int mt = 0; mt < 4; ++mt)
            #pragma unroll
            for (int nt = 0; nt < 2; ++nt) {
                int m0 = rowb + wm + mt * 16 + quad * 4;
                int n = colb + wn + nt * 16 + l15;
                ushort4 o;
                o.x = f2bbits(acc[mt][nt][0] + bvv[nt]);
                o.y = f2bbits(acc[mt][nt][1] + bvv[nt]);
                o.z = f2bbits(acc[mt][nt][2] + bvv[nt]);
                o.w = f2bbits(acc[mt][nt][3] + bvv[nt]);
                *(ushort4*)&VT[(size_t)n * S + m0] = o;
            }
    } else {
        bf16* out = (blockIdx.z == 0) ? Qb : Kb;
        const float scale = (blockIdx.z == 1) ? 0.125f : 1.0f;
        #pragma unroll
        for (int mt = 0; mt < 4; ++mt)
            #pragma unroll
            for (int nt = 0; nt < 2; ++nt)
                #pragma unroll
                for (int r = 0; r < 4; ++r) {
                    int m = rowb + wm + mt * 16 + quad * 4 + r;
                    int n = colb + wn + nt * 16 + l15;
                    out[(size_t)m * H + n] =
                        __float2bfloat16((acc[mt][nt][r] + bvv[nt]) * scale);
                }
    }
}

// ---------------- output MFMA GEMM (64x64 tiles, 512 blocks = 2/CU) --------
__global__ __launch_bounds__(256) void out_mfma(
    const bf16* __restrict__ Cb, const bf16* __restrict__ WoT,
    const void* __restrict__ bias, void* __restrict__ out,
    const int* __restrict__ flag)
{
    const int f = *flag;
    f32x4 acc[2][2];
    #pragma unroll
    for (int a = 0; a < 2; ++a)
        #pragma unroll
        for (int b = 0; b < 2; ++b) acc[a][b] = (f32x4)0.f;

    gemm_bt_core<64, 64>(Cb, WoT, acc);

    const int tid = threadIdx.x;
    const int w = tid >> 6, lane = tid & 63;
    const int l15 = lane & 15, quad = lane >> 4;
    const int wm = (w & 1) * 32, wn = (w >> 1) * 32;
    const int rowb = blockIdx.y * 64;
    const int colb = blockIdx.x * 64;

    float bvv[2];
    #pragma unroll
    for (int nt = 0; nt < 2; ++nt)
        bvv[nt] = ldf(bias, colb + wn + nt * 16 + l15, f);

    #pragma unroll
    for (int mt = 0; mt < 2; ++mt)
        #pragma unroll
        for (int nt = 0; nt < 2; ++nt)
            #pragma unroll
            for (int r = 0; r < 4; ++r) {
                int m = rowb + wm + mt * 16 + quad * 4 + r;
                int n = colb + wn + nt * 16 + l15;
                float v = acc[mt][nt][r] + bvv[nt];
                if (f) ((float*)out)[(size_t)m * H + n] = v;
                else   ((bf16*)out)[(size_t)m * H + n] = __float2bfloat16(v);
            }
}

// ---------------- MFMA flash attention (R12 best-known structure) ----------
__global__ __launch_bounds__(256, 4) void attn_mfma(
    const bf16* __restrict__ Qb, const bf16* __restrict__ Kb,
    const bf16* __restrict__ VT,
    const void* __restrict__ rel_emb, const void* __restrict__ rel_bias,
    const unsigned char* __restrict__ PBg,
    float* __restrict__ Op, float* __restrict__ Lp,
    const int* __restrict__ flag)
{
    const int h = blockIdx.x;
    const int qb = blockIdx.y;
    const int split = blockIdx.z;
    const int q0 = qb * 64;
    const int kt0 = split * SKEYS;
    const int tid = threadIdx.x;
    const int w = tid >> 6;
    const int lane = tid & 63;
    const int l15 = lane & 15;
    const int quad = lane >> 4;
    const int f = *flag;

    __shared__ short Ks[64][80];
    __shared__ short Vs[64][80];
    __shared__ float Rl[64][33];
    __shared__ float Rbias[32];
    union SharedU {
        short Es[32][64];
        short Ps[64][72];
    };
    __shared__ SharedU U;

    const unsigned char* pbrow = PBg + (size_t)(q0 + w * 16 + l15) * S;

    uint4 kp[2], vp[2];
    unsigned int pb[4];
    {
        #pragma unroll
        for (int j = 0; j < 2; ++j) {
            int slot = j * 256 + tid;
            int r = slot >> 3, c = slot & 7;
            kp[j] = *(const uint4*)&Kb[(size_t)(kt0 + r) * H + h * DH + c * 8];
            vp[j] = *(const uint4*)&VT[(size_t)(h * DH + r) * S + kt0 + c * 8];
        }
        #pragma unroll
        for (int nt = 0; nt < 4; ++nt)
            pb[nt] = *(const unsigned int*)&pbrow[kt0 + nt * 16 + quad * 4];
    }

    bf16x8 aq0, aq1;
    {
        const bf16* qrow = Qb + (size_t)(q0 + w * 16 + l15) * H + h * DH;
        aq0 = *(const bf16x8*)&qrow[quad * 8];
        aq1 = *(const bf16x8*)&qrow[32 + quad * 8];
    }

    {
        int r = tid >> 3, c8 = (tid & 7) * 8;
        unsigned short os[8];
        if (f) {
            const float* src = (const float*)rel_emb + (r * NH + h) * DH + c8;
            #pragma unroll
            for (int e = 0; e < 8; ++e) os[e] = f2bbits(src[e] * 0.125f);
        } else {
            const bf16* src = (const bf16*)rel_emb + (r * NH + h) * DH + c8;
            #pragma unroll
            for (int e = 0; e < 8; ++e) os[e] = f2bbits(b2f(src[e]) * 0.125f);
        }
        *(ushort4*)&U.Es[r][c8]     = *(ushort4*)&os[0];
        *(ushort4*)&U.Es[r][c8 + 4] = *(ushort4*)&os[4];
        if (tid < RV) Rbias[tid] = ldf(rel_bias, tid * NH + h, f) * 0.125f;
    }
    __syncthreads();

    #pragma unroll
    for (int nt = 0; nt < 2; ++nt) {
        bf16x8 be0 = *(const bf16x8*)&U.Es[nt * 16 + l15][quad * 8];
        bf16x8 be1 = *(const bf16x8*)&U.Es[nt * 16 + l15][32 + quad * 8];
        f32x4 c = (f32x4)0.f;
        c = __builtin_amdgcn_mfma_f32_16x16x32_bf16(aq0, be0, c, 0, 0, 0);
        c = __builtin_amdgcn_mfma_f32_16x16x32_bf16(aq1, be1, c, 0, 0, 0);
        float rb = Rbias[nt * 16 + l15];
        #pragma unroll
        for (int r = 0; r < 4; ++r)
            Rl[w * 16 + quad * 4 + r][nt * 16 + l15] = c[r] + rb;
    }
    __syncthreads();

    f32x4 O[4];
    #pragma unroll
    for (int i = 0; i < 4; ++i) O[i] = (f32x4)0.f;
    float llocal = 0.f;
    const float* rlrow = &Rl[w * 16 + l15][0];

    for (int kt = kt0; kt < kt0 + SKEYS; kt += 64) {
        #pragma unroll
        for (int j = 0; j < 2; ++j) {
            int slot = j * 256 + tid;
            int r = slot >> 3, c = slot & 7;
            *(uint4*)&Ks[r][c * 8] = kp[j];
            *(uint4*)&Vs[r][c * 8] = vp[j];
        }
        unsigned int pbc[4];
        #pragma unroll
        for (int nt = 0; nt < 4; ++nt) pbc[nt] = pb[nt];
        __syncthreads();

        if (kt + 64 < kt0 + SKEYS) {
            #pragma unroll
            for (int j = 0; j < 2; ++j) {
                int slot = j * 256 + tid;
                int r = slot >> 3, c = slot & 7;
                kp[j] = *(const uint4*)&Kb[(size_t)(kt + 64 + r) * H + h * DH + c * 8];
                vp[j] = *(const uint4*)&VT[(size_t)(h * DH + r) * S + kt + 64 + c * 8];
            }
            #pragma unroll
            for (int nt = 0; nt < 4; ++nt)
                pb[nt] = *(const unsigned int*)&pbrow[kt + 64 + nt * 16 + quad * 4];
        }

        f32x4 sc[4];
        #pragma unroll
        for (int nt = 0; nt < 4; ++nt) {
            bf16x8 ak0 = *(const bf16x8*)&Ks[nt * 16 + l15][quad * 8];
            bf16x8 ak1 = *(const bf16x8*)&Ks[nt * 16 + l15][32 + quad * 8];
            f32x4 c = (f32x4)0.f;
            c = __builtin_amdgcn_mfma_f32_16x16x32_bf16(ak0, aq0, c, 0, 0, 0);
            c = __builtin_amdgcn_mfma_f32_16x16x32_bf16(ak1, aq1, c, 0, 0, 0);
            sc[nt] = c;
        }

        #pragma unroll
        for (int nt = 0; nt < 4; ++nt) {
            unsigned int pw = pbc[nt];
            #pragma unroll
            for (int r = 0; r < 4; ++r) {
                unsigned int b = pw >> (8 * r);
                float rl = rlrow[b & 63u];
                float p = __expf(sc[nt][r] + rl);
                p = (b & 0x80u) ? 0.f : p;
                sc[nt][r] = p;
            }
            llocal += (sc[nt][0] + sc[nt][1]) + (sc[nt][2] + sc[nt][3]);
            ushort4 o;
            o.x = f2bbits(sc[nt][0]); o.y = f2bbits(sc[nt][1]);
            o.z = f2bbits(sc[nt][2]); o.w = f2bbits(sc[nt][3]);
            *(ushort4*)&U.Ps[w * 16 + l15][nt * 16 + quad * 4] = o;
        }

        bf16x8 ap0 = *(const bf16x8*)&U.Ps[w * 16 + l15][quad * 8];
        bf16x8 ap1 = *(const bf16x8*)&U.Ps[w * 16 + l15][32 + quad * 8];
        #pragma unroll
        for (int dt = 0; dt < 4; ++dt) {
            bf16x8 bv0 = *(const bf16x8*)&Vs[dt * 16 + l15][quad * 8];
            bf16x8 bv1 = *(const bf16x8*)&Vs[dt * 16 + l15][32 + quad * 8];
            O[dt] = __builtin_amdgcn_mfma_f32_16x16x32_bf16(ap0, bv0, O[dt], 0, 0, 0);
            O[dt] = __builtin_amdgcn_mfma_f32_16x16x32_bf16(ap1, bv1, O[dt], 0, 0, 0);
        }
        __syncthreads();
    }

    float lsum = llocal;
    lsum += __shfl_xor(lsum, 16, 64);
    lsum += __shfl_xor(lsum, 32, 64);

    const size_t base = ((size_t)split * NH + h) * 32 + qb;
    float* Ob = Op + base * 4096;
    #pragma unroll
    for (int r = 0; r < 4; ++r) {
        int qr = w * 16 + quad * 4 + r;
        #pragma unroll
        for (int dt = 0; dt < 4; ++dt)
            Ob[qr * 64 + dt * 16 + l15] = O[dt][r];
    }
    if (quad == 0) Lp[base * 64 + w * 16 + l15] = lsum;
}

// ---------------- merge split partials -> Cb bf16 --------------------------
__global__ __launch_bounds__(256) void reduce_splits(
    const float* __restrict__ Op, const float* __restrict__ Lp,
    bf16* __restrict__ Cb)
{
    const int h = blockIdx.x;
    const int qb = blockIdx.y;
    const int q0 = qb * 64;
    const int tid = threadIdx.x;
    const int q = tid >> 2;
    const int d0 = (tid & 3) * 16;

    const size_t b0 = ((size_t)0 * NH + h) * 32 + qb;
    const size_t b1 = ((size_t)1 * NH + h) * 32 + qb;

    float l = Lp[b0 * 64 + q] + Lp[b1 * 64 + q];
    float inv = 1.0f / l;

    const float4* O0 = (const float4*)(Op + b0 * 4096 + q * 64 + d0);
    const float4* O1 = (const float4*)(Op + b1 * 4096 + q * 64 + d0);
    bf16* outp = Cb + (size_t)(q0 + q) * H + h * DH + d0;
    #pragma unroll
    for (int j = 0; j < 4; ++j) {
        float4 v0 = O0[j], v1 = O1[j];
        ushort4 o;
        o.x = f2bbits((v0.x + v1.x) * inv);
        o.y = f2bbits((v0.y + v1.y) * inv);
        o.z = f2bbits((v0.z + v1.z) * inv);
        o.w = f2bbits((v0.w + v1.w) * inv);
        *(ushort4*)&outp[j * 4] = o;
    }
}

extern "C" void kernel_launch(void* const* d_in, const int* in_sizes, int n_in,
                              void* d_out, int out_size, void* d_ws, size_t ws_size,
                              hipStream_t stream)
{
    const void* x        = d_in[0];
    const int*  att_mask = (const int*)d_in[1];
    const int*  rel_ids  = (const int*)d_in[2];
    const void* Wq = d_in[3];
    const void* bq = d_in[4];
    const void* Wk = d_in[5];
    const void* bk = d_in[6];
    const void* Wv = d_in[7];
    const void* bv = d_in[8];
    const void* rel_emb  = d_in[9];
    const void* rel_bias = d_in[10];
    const void* Wo = d_in[11];
    const void* bo = d_in[12];

    char* p = (char*)d_ws;
    bf16* xb  = (bf16*)p; p += (size_t)S * H * 2;
    bf16* WTq = (bf16*)p; p += (size_t)H * H * 2;
    bf16* WTk = (bf16*)p; p += (size_t)H * H * 2;
    bf16* WTv = (bf16*)p; p += (size_t)H * H * 2;
    bf16* WoT = (bf16*)p; p += (size_t)H * H * 2;
    bf16* Qb  = (bf16*)p; p += (size_t)S * H * 2;
    bf16* Kb  = (bf16*)p; p += (size_t)S * H * 2;
    bf16* VT  = (bf16*)p; p += (size_t)S * H * 2;
    bf16* Cb  = (bf16*)p; p += (size_t)S * H * 2;
    unsigned char* PBg = (unsigned char*)p; p += (size_t)S * S;
    float* Op = (float*)p; p += (size_t)NSPLIT * NH * 32 * 64 * 64 * 4;
    float* Lp = (float*)p; p += (size_t)NSPLIT * NH * 32 * 64 * 4;
    int* flag = (int*)p;

    prep_inputs<<<dim3(H / 64, H / 64, 9), 256, 0, stream>>>(
        Wq, Wk, Wv, Wo, WTq, WTk, WTv, WoT, x, xb,
        rel_ids, att_mask, PBg, flag);

    qkv_mfma<<<dim3(H / 64, S / 128, 3), 256, 0, stream>>>(
        xb, WTq, WTk, WTv, bq, bk, bv, Qb, Kb, VT, flag);

    attn_mfma<<<dim3(NH, S / 64, NSPLIT), 256, 0, stream>>>(
        Qb, Kb, VT, rel_emb, rel_bias, PBg, Op, Lp, flag);

    reduce_splits<<<dim3(NH, S / 64), 256, 0, stream>>>(Op, Lp, Cb);

    out_mfma<<<dim3(H / 64, S / 64), 256, 0, stream>>>(Cb, WoT, bo, d_out, flag);
}